// Round 14
// baseline (601.058 us; speedup 1.0000x reference)
//
#include <hip/hip_runtime.h>
#include <hip/hip_fp16.h>
#include <math.h>

#define HID   64
#define HEADS 4
#define DH    16
#define NU    30000
#define NE_   60000
#define NV    1000
#define NTOT  91000
#define ETOT  870000
#define NSLOT 541000
#define LAYERS 2
#define LOG2E 1.44269504088896340736f

// Edge-type tables
__device__ const int d_EOFF[14] = {0,150000,270000,330000,370000,400000,450000,
                                   570000,630000,670000,700000,750000,810000,870000};
__device__ const int d_ECNT[13] = {150000,120000,60000,40000,30000,50000,
                                   120000,60000,40000,30000,50000,60000,60000};
__device__ const int d_EST[13]  = {0,0,0,0,0,0,1,1,1,1,1,1,2};
__device__ const int d_EDT[13]  = {0,1,1,1,1,1,0,0,0,0,0,2,1};
__device__ const int d_NOFF[3]  = {0, NU, NU + NE_};
// slot base per edge type in the kvt mega-table (src-node indexed per e)
__device__ const int d_EBASE[13] = {0,30000,60000,90000,120000,150000,
                                    180000,240000,300000,360000,420000,480000,540000};

struct EdgePtrs { const int* p[13]; };

typedef float f32x2 __attribute__((ext_vector_type(2)));

__device__ __forceinline__ void pk_fma(f32x2& acc, f32x2 a, f32x2 b) {
    asm("v_pk_fma_f32 %0, %1, %2, %0" : "+v"(acc) : "v"(a), "v"(b));
}
// a is wave-uniform (SGPR pair) -> VOP3P scalar source, no v_mov marshalling.
__device__ __forceinline__ void pk_fma_sv(f32x2& acc, f32x2 a_sgpr, f32x2 b) {
    asm("v_pk_fma_f32 %0, %1, %2, %0" : "+v"(acc) : "s"(a_sgpr), "v"(b));
}

__device__ __forceinline__ int node_type(int n) {
    return (n >= NU) + (n >= NU + NE_);
}

// ---------------- input projection: h = x@W + b + emb[ids] ----------------
__global__ __launch_bounds__(64)
void k_init(const float* __restrict__ xu, const float* __restrict__ xe,
            const float* __restrict__ xv,
            const float* __restrict__ Wu, const float* __restrict__ bu,
            const float* __restrict__ We, const float* __restrict__ be,
            const float* __restrict__ Wv_, const float* __restrict__ bv,
            const float* __restrict__ embu, const float* __restrict__ embe,
            const float* __restrict__ embv,
            const int* __restrict__ idu, const int* __restrict__ ide,
            const int* __restrict__ idv,
            float* __restrict__ h) {
    int n0 = blockIdx.x * 16;
    int t = node_type(n0);          // 16-node tiles never straddle type boundaries
    int j = threadIdx.x;            // output column 0..63
    const float *x, *W, *bb, *emb; const int* ids; int in_dim;
    if (t == 0)      { x = xu; W = Wu;  bb = bu; emb = embu; ids = idu; in_dim = 32; }
    else if (t == 1) { x = xe; W = We;  bb = be; emb = embe; ids = ide; in_dim = 32; }
    else             { x = xv; W = Wv_; bb = bv; emb = embv; ids = idv; in_dim = 16; }
    int nl = n0 - d_NOFF[t];
    int nn = min(16, NTOT - n0);
    __shared__ float xT[32][20];    // transposed x tile, +4 pad
    int ncs = (in_dim == 32) ? 3 : 2;       // log2 float4-chunks per node
    int nch = 1 << ncs;
    for (int idx = j; idx < (nch << 4); idx += 64) {
        int n = idx >> ncs, c = idx & (nch - 1);
        float4 v = make_float4(0.f, 0.f, 0.f, 0.f);
        if (n < nn) v = *(const float4*)(x + (size_t)(nl + n) * in_dim + c * 4);
        xT[c * 4 + 0][n] = v.x;
        xT[c * 4 + 1][n] = v.y;
        xT[c * 4 + 2][n] = v.z;
        xT[c * 4 + 3][n] = v.w;
    }
    __syncthreads();
    float bj = bb[j];
    f32x2 acc2[8];
    #pragma unroll
    for (int p = 0; p < 8; p++) {
        float ex = (2 * p     < nn) ? emb[(size_t)ids[nl + 2 * p    ] * 64 + j] : 0.f;
        float ey = (2 * p + 1 < nn) ? emb[(size_t)ids[nl + 2 * p + 1] * 64 + j] : 0.f;
        acc2[p].x = bj + ex; acc2[p].y = bj + ey;
    }
    if (in_dim == 32) {
        #pragma unroll
        for (int i = 0; i < 32; i++) {
            float w = W[i * 64 + j];
            f32x2 w2; w2.x = w; w2.y = w;
            #pragma unroll
            for (int qd = 0; qd < 4; qd++) {
                float4 hv = *(const float4*)(&xT[i][qd * 4]);
                f32x2 p0; p0.x = hv.x; p0.y = hv.y; pk_fma(acc2[2 * qd],     p0, w2);
                f32x2 p1; p1.x = hv.z; p1.y = hv.w; pk_fma(acc2[2 * qd + 1], p1, w2);
            }
        }
    } else {
        #pragma unroll
        for (int i = 0; i < 16; i++) {
            float w = W[i * 64 + j];
            f32x2 w2; w2.x = w; w2.y = w;
            #pragma unroll
            for (int qd = 0; qd < 4; qd++) {
                float4 hv = *(const float4*)(&xT[i][qd * 4]);
                f32x2 p0; p0.x = hv.x; p0.y = hv.y; pk_fma(acc2[2 * qd],     p0, w2);
                f32x2 p1; p1.x = hv.z; p1.y = hv.w; pk_fma(acc2[2 * qd + 1], p1, w2);
            }
        }
    }
    #pragma unroll
    for (int p = 0; p < 8; p++) {
        if (2 * p     < nn) h[(size_t)(n0 + 2 * p)     * 64 + j] = acc2[p].x;
        if (2 * p + 1 < nn) h[(size_t)(n0 + 2 * p + 1) * 64 + j] = acc2[p].y;
    }
}

// ---------------- CSR build (single-atomic-pass, R15) ----------------
__global__ void k_cnt(EdgePtrs ep, int* __restrict__ cnt, int* __restrict__ pos) {
    int eidx = blockIdx.x * blockDim.x + threadIdx.x;
    if (eidx >= ETOT) return;
    int e = 0;
    #pragma unroll
    for (int i = 1; i < 13; i++) e += (eidx >= d_EOFF[i]);
    int li = eidx - d_EOFF[e];
    int dst = ep.p[e][d_ECNT[e] + li];
    pos[eidx] = atomicAdd(&cnt[d_NOFF[d_EDT[e]] + dst], 1);
}

__global__ void k_scan_a(const int* __restrict__ cnt, int* __restrict__ partial) {
    __shared__ int s[256];
    int i = blockIdx.x * 256 + threadIdx.x;
    s[threadIdx.x] = (i < NTOT) ? cnt[i] : 0;
    __syncthreads();
    for (int off = 128; off > 0; off >>= 1) {
        if (threadIdx.x < off) s[threadIdx.x] += s[threadIdx.x + off];
        __syncthreads();
    }
    if (threadIdx.x == 0) partial[blockIdx.x] = s[0];
}

__global__ void k_scan_b(int* __restrict__ partial, int nblk) {
    __shared__ int s[512];
    int t = threadIdx.x;
    s[t] = (t < nblk) ? partial[t] : 0;
    __syncthreads();
    for (int off = 1; off < 512; off <<= 1) {
        int v = (t >= off) ? s[t - off] : 0;
        __syncthreads();
        s[t] += v;
        __syncthreads();
    }
    if (t < nblk) partial[t] = t ? s[t - 1] : 0;   // exclusive
}

__global__ void k_scan_c(const int* __restrict__ cnt, const int* __restrict__ partial,
                         int* __restrict__ row_ptr) {
    __shared__ int s[256];
    int i = blockIdx.x * 256 + threadIdx.x, t = threadIdx.x;
    int v = (i < NTOT) ? cnt[i] : 0;
    s[t] = v;
    __syncthreads();
    for (int off = 1; off < 256; off <<= 1) {
        int u = (t >= off) ? s[t - off] : 0;
        __syncthreads();
        s[t] += u;
        __syncthreads();
    }
    if (i < NTOT) row_ptr[i] = s[t] - v + partial[blockIdx.x];
    if (i == NTOT - 1) row_ptr[NTOT] = s[t] + partial[blockIdx.x];
}

__global__ void k_fill(EdgePtrs ep, const int* __restrict__ row_ptr,
                       const int* __restrict__ pos, int* __restrict__ csr) {
    int eidx = blockIdx.x * blockDim.x + threadIdx.x;
    if (eidx >= ETOT) return;
    int e = 0;
    #pragma unroll
    for (int i = 1; i < 13; i++) e += (eidx >= d_EOFF[i]);
    int li = eidx - d_EOFF[e];
    const int* base = ep.p[e];
    int src = base[li], dst = base[d_ECNT[e] + li];
    int dg = d_NOFF[d_EDT[e]] + dst;
    csr[row_ptr[dg] + pos[eidx]] = d_EBASE[e] + src;   // no atomic
}

// ---------------- fused kqv projection + kvt slot table build ----------------
// R12 structure (local optimum: 95.5us, VALU+DS co-bound).
// R18-kept: q written PRE-SCALED by log2(e) so the gather softmax runs in the
// base-2 domain (exp2f = bare v_exp_f32, saves the per-exp mul).
__global__ __launch_bounds__(192, 3)
void k_kqvt(const float* __restrict__ h, const float* __restrict__ Wkqv,
            const float* __restrict__ bkqv, const float* __restrict__ Wk,
            const float* __restrict__ Wv, const float* __restrict__ prel,
            float* __restrict__ qagg, __half2* __restrict__ kvt, int layer) {
    int n0 = blockIdx.x * 16;
    int t = node_type(n0);          // 16-node tiles never straddle type boundaries
    __shared__ float kq[16][192];   // per node: k 0..63 | q 64..127 | v 128..191
    int j = threadIdx.x;

    // ---- stage 1: column j of kqv for 16 nodes; uniform global h reads
    const float* hb = h + (size_t)n0 * 64;
    const float* Wc = Wkqv + (size_t)(layer * 3 + t) * HID * 192 + j;
    float b = bkqv[(layer * 3 + t) * 192 + j];
    f32x2 acc2[16];
    #pragma unroll
    for (int n = 0; n < 16; n++) { acc2[n].x = 0.f; acc2[n].y = 0.f; }
    #pragma unroll
    for (int ic = 0; ic < 16; ic++) {
        float w0 = Wc[(size_t)(4 * ic + 0) * 192];
        float w1 = Wc[(size_t)(4 * ic + 1) * 192];
        float w2 = Wc[(size_t)(4 * ic + 2) * 192];
        float w3 = Wc[(size_t)(4 * ic + 3) * 192];
        f32x2 wA; wA.x = w0; wA.y = w1;
        f32x2 wB; wB.x = w2; wB.y = w3;
        #pragma unroll
        for (int n = 0; n < 16; n++) {
            float4 hv = *(const float4*)(hb + n * 64 + ic * 4);  // block-uniform
            f32x2 p0; p0.x = hv.x; p0.y = hv.y;
            pk_fma_sv(acc2[n], p0, wA);
            f32x2 p1; p1.x = hv.z; p1.y = hv.w;
            pk_fma_sv(acc2[n], p1, wB);
        }
    }
    float accf[16];
    #pragma unroll
    for (int n = 0; n < 16; n++) accf[n] = b + acc2[n].x + acc2[n].y;
    #pragma unroll
    for (int n = 0; n < 16; n++) kq[n][j] = accf[n];
    if (j >= 64 && j < 128) {
        #pragma unroll
        for (int n = 0; n < 16; n++)
            if (n0 + n < NTOT) qagg[(size_t)(n0 + n) * 64 + (j - 64)] = accf[n] * LOG2E;
    }
    __syncthreads();

    // ---- stage 2: emit kvt slots for the edge types sourced by this node type
    int wave = j >> 6, lane = j & 63;
    int hh = lane >> 4, xo = lane & 15;
    int ne = (t == 2) ? 1 : 6;
    int e0 = (t == 0) ? 0 : (t == 1) ? 6 : 12;
    int eA = e0 + wave, eB = e0 + wave + 3;
    bool vA = wave < ne, vB = wave + 3 < ne;
    int nt = n0 - d_NOFF[t];
    f32x2 wkA[8], wvA[8], wkB[8], wvB[8];
    int sbA = 0, sbB = 0;
    if (vA) {
        const float* Wkp = Wk + (((size_t)layer * 13 + eA) * 4 + hh) * 256 + xo;
        const float* Wvp = Wv + (((size_t)layer * 13 + eA) * 4 + hh) * 256 + xo;
        float pr = prel[(layer * 13 + eA) * 4 + hh] * 0.25f;
        #pragma unroll
        for (int p = 0; p < 8; p++) {
            wkA[p].x = Wkp[(2 * p)     * 16] * pr;
            wkA[p].y = Wkp[(2 * p + 1) * 16] * pr;
            wvA[p].x = Wvp[(2 * p)     * 16];
            wvA[p].y = Wvp[(2 * p + 1) * 16];
        }
        sbA = d_EBASE[eA] + nt;
    }
    if (vB) {
        const float* Wkp = Wk + (((size_t)layer * 13 + eB) * 4 + hh) * 256 + xo;
        const float* Wvp = Wv + (((size_t)layer * 13 + eB) * 4 + hh) * 256 + xo;
        float pr = prel[(layer * 13 + eB) * 4 + hh] * 0.25f;
        #pragma unroll
        for (int p = 0; p < 8; p++) {
            wkB[p].x = Wkp[(2 * p)     * 16] * pr;
            wkB[p].y = Wkp[(2 * p + 1) * 16] * pr;
            wvB[p].x = Wvp[(2 * p)     * 16];
            wvB[p].y = Wvp[(2 * p + 1) * 16];
        }
        sbB = d_EBASE[eB] + nt;
    }
    #pragma unroll
    for (int n = 0; n < 16; n++) {
        bool ok = (n0 + n) < NTOT;                 // uniform; false only in tail tile
        const float* kr = &kq[n][hh * 16];
        const float* vr = &kq[n][128 + hh * 16];
        float4 k0 = ((const float4*)kr)[0];
        float4 k1 = ((const float4*)kr)[1];
        float4 k2 = ((const float4*)kr)[2];
        float4 k3 = ((const float4*)kr)[3];
        float4 v0 = ((const float4*)vr)[0];
        float4 v1 = ((const float4*)vr)[1];
        float4 v2 = ((const float4*)vr)[2];
        float4 v3 = ((const float4*)vr)[3];
        if (vA & ok) {
            f32x2 ak; ak.x = 0.f; ak.y = 0.f;
            f32x2 av; av.x = 0.f; av.y = 0.f;
            f32x2 p0;
            p0.x = k0.x; p0.y = k0.y; pk_fma(ak, p0, wkA[0]);
            p0.x = k0.z; p0.y = k0.w; pk_fma(ak, p0, wkA[1]);
            p0.x = k1.x; p0.y = k1.y; pk_fma(ak, p0, wkA[2]);
            p0.x = k1.z; p0.y = k1.w; pk_fma(ak, p0, wkA[3]);
            p0.x = k2.x; p0.y = k2.y; pk_fma(ak, p0, wkA[4]);
            p0.x = k2.z; p0.y = k2.w; pk_fma(ak, p0, wkA[5]);
            p0.x = k3.x; p0.y = k3.y; pk_fma(ak, p0, wkA[6]);
            p0.x = k3.z; p0.y = k3.w; pk_fma(ak, p0, wkA[7]);
            p0.x = v0.x; p0.y = v0.y; pk_fma(av, p0, wvA[0]);
            p0.x = v0.z; p0.y = v0.w; pk_fma(av, p0, wvA[1]);
            p0.x = v1.x; p0.y = v1.y; pk_fma(av, p0, wvA[2]);
            p0.x = v1.z; p0.y = v1.w; pk_fma(av, p0, wvA[3]);
            p0.x = v2.x; p0.y = v2.y; pk_fma(av, p0, wvA[4]);
            p0.x = v2.z; p0.y = v2.w; pk_fma(av, p0, wvA[5]);
            p0.x = v3.x; p0.y = v3.y; pk_fma(av, p0, wvA[6]);
            p0.x = v3.z; p0.y = v3.w; pk_fma(av, p0, wvA[7]);
            float kt = ak.x + ak.y;
            float vt = av.x + av.y;
            kvt[(size_t)(sbA + n) * 64 + lane] = __float22half2_rn(make_float2(kt, vt));
        }
        if (vB & ok) {
            f32x2 ak; ak.x = 0.f; ak.y = 0.f;
            f32x2 av; av.x = 0.f; av.y = 0.f;
            f32x2 p0;
            p0.x = k0.x; p0.y = k0.y; pk_fma(ak, p0, wkB[0]);
            p0.x = k0.z; p0.y = k0.w; pk_fma(ak, p0, wkB[1]);
            p0.x = k1.x; p0.y = k1.y; pk_fma(ak, p0, wkB[2]);
            p0.x = k1.z; p0.y = k1.w; pk_fma(ak, p0, wkB[3]);
            p0.x = k2.x; p0.y = k2.y; pk_fma(ak, p0, wkB[4]);
            p0.x = k2.z; p0.y = k2.w; pk_fma(ak, p0, wkB[5]);
            p0.x = k3.x; p0.y = k3.y; pk_fma(ak, p0, wkB[6]);
            p0.x = k3.z; p0.y = k3.w; pk_fma(ak, p0, wkB[7]);
            p0.x = v0.x; p0.y = v0.y; pk_fma(av, p0, wvB[0]);
            p0.x = v0.z; p0.y = v0.w; pk_fma(av, p0, wvB[1]);
            p0.x = v1.x; p0.y = v1.y; pk_fma(av, p0, wvB[2]);
            p0.x = v1.z; p0.y = v1.w; pk_fma(av, p0, wvB[3]);
            p0.x = v2.x; p0.y = v2.y; pk_fma(av, p0, wvB[4]);
            p0.x = v2.z; p0.y = v2.w; pk_fma(av, p0, wvB[5]);
            p0.x = v3.x; p0.y = v3.y; pk_fma(av, p0, wvB[6]);
            p0.x = v3.z; p0.y = v3.w; pk_fma(av, p0, wvB[7]);
            float kt = ak.x + ak.y;
            float vt = av.x + av.y;
            kvt[(size_t)(sbB + n) * 64 + lane] = __float22half2_rn(make_float2(kt, vt));
        }
    }
}

// -------- fused gather + cooperative epilogue (R17 + base-2 softmax) --------
// R19: gather addressing reverted to R11's 64-bit index form (R18's manual
// saddr arithmetic put a dependent v_lshl_add on every load and regressed
// +4us). Base-2 softmax kept: q pre-scaled by log2e, exp2f everywhere.
__device__ __forceinline__ float row_sum16(float x) {
    int v;
    v = __builtin_amdgcn_update_dpp(0, __float_as_int(x), 0xB1, 0xF, 0xF, true); // quad_perm [1,0,3,2] : xor1
    x += __int_as_float(v);
    v = __builtin_amdgcn_update_dpp(0, __float_as_int(x), 0x4E, 0xF, 0xF, true); // quad_perm [2,3,0,1] : xor2
    x += __int_as_float(v);
    v = __builtin_amdgcn_update_dpp(0, __float_as_int(x), 0x141, 0xF, 0xF, true); // row_half_mirror : xor4
    x += __int_as_float(v);
    v = __builtin_amdgcn_update_dpp(0, __float_as_int(x), 0x140, 0xF, 0xF, true); // row_mirror : xor8
    x += __int_as_float(v);
    return x;
}

__device__ __forceinline__ void osm_step(float s, float vv,
                                         float& m, float& l, float& acc) {
    float d = s - m;                // base-2 domain
    float t = exp2f(-fabsf(d));     // bare v_exp_f32
    bool pos = d > 0.f;
    m = fmaxf(m, s);
    float sc = pos ? t : 1.f;
    float es = pos ? 1.f : t;
    l   = l * sc + es;
    acc = acc * sc + es * vv;
}

__global__ __launch_bounds__(512, 4)
void k_gather(const float* __restrict__ qagg, const __half2* __restrict__ kvt,
              const int* __restrict__ row_ptr, const int* __restrict__ csr,
              const float* __restrict__ Wout, const float* __restrict__ bout,
              const float* __restrict__ skip,
              float* __restrict__ h, float* __restrict__ out,
              int layer, int last) {
    int wave = threadIdx.x >> 6, lane = threadIdx.x & 63;
    int node = blockIdx.x * 8 + wave;            // grid is exact: no tail
    int t = node_type(node);                     // block-uniform
    // prefetches whose latency hides under the gather loop
    float hprev = h[(size_t)node * 64 + lane];
    float bb = bout[(layer * 3 + t) * 64 + lane];
    float gk = 1.f / (1.f + __expf(-skip[layer * 3 + t]));
    float q = qagg[(size_t)node * 64 + lane];    // q[h][x], pre-scaled by log2e
    int beg = row_ptr[node], end = row_ptr[node + 1];
    float m0 = -1e30f, l0 = 0.f, a0 = 0.f;       // chain 0 (edges k%4==0)
    float m1 = -1e30f, l1 = 0.f, a1 = 0.f;       // chain 1
    float m2 = -1e30f, l2 = 0.f, a2 = 0.f;       // chain 2
    float m3 = -1e30f, l3 = 0.f, a3 = 0.f;       // chain 3
    for (int base = beg; base < end; base += 64) {
        int n = end - base; if (n > 64) n = 64;
        int ent = csr[base + ((lane < n) ? lane : 0)];   // 64 entries in one load
        for (int c = 0; c < n; c += 8) {
            int cn = n - c; if (cn > 8) cn = 8;
            __half2 f[8];
            #pragma unroll
            for (int k = 0; k < 8; k++) {               // batch 8 gathers (MLP)
                int idx = c + ((k < cn) ? k : 0);
                int sl = __shfl(ent, idx, 64);
                f[k] = kvt[(size_t)sl * 64 + lane];
            }
            float s8[8];
            #pragma unroll
            for (int k = 0; k < 8; k++) {               // 8 independent reductions
                if (k >= cn) break;                     // uniform branch
                s8[k] = row_sum16(q * __low2float(f[k]));
            }
            // 4 interleaved chains: dependent depth 2 per batch
            if (0 < cn) osm_step(s8[0], __high2float(f[0]), m0, l0, a0);
            if (1 < cn) osm_step(s8[1], __high2float(f[1]), m1, l1, a1);
            if (2 < cn) osm_step(s8[2], __high2float(f[2]), m2, l2, a2);
            if (3 < cn) osm_step(s8[3], __high2float(f[3]), m3, l3, a3);
            if (4 < cn) osm_step(s8[4], __high2float(f[4]), m0, l0, a0);
            if (5 < cn) osm_step(s8[5], __high2float(f[5]), m1, l1, a1);
            if (6 < cn) osm_step(s8[6], __high2float(f[6]), m2, l2, a2);
            if (7 < cn) osm_step(s8[7], __high2float(f[7]), m3, l3, a3);
        }
    }
    // merge the four online-softmax states (base-2 domain)
    float M   = fmaxf(fmaxf(m0, m1), fmaxf(m2, m3));
    float e0  = exp2f(m0 - M), e1 = exp2f(m1 - M);
    float e2  = exp2f(m2 - M), e3 = exp2f(m3 - M);
    float l   = l0 * e0 + l1 * e1 + l2 * e2 + l3 * e3;
    float acc = a0 * e0 + a1 * e1 + a2 * e2 + a3 * e3;
    float og  = (l > 0.f) ? acc / l : 0.f;

    // ---- cooperative epilogue ----
    float gl = 0.5f * og * (1.f + erff(og * 0.70710678118654752f));   // gelu
    __shared__ float gsT[64][12];       // gsT[i][n]; 48B rows (16B-aligned)
    __shared__ float part[8][8][64];    // part[g][n][j]
    gsT[lane][wave] = gl;
    __syncthreads();
    // thread (g=wave, j=lane): partial over i in [8g, 8g+8) for all 8 nodes
    const float* Wb = Wout + (size_t)(layer * 3 + t) * 4096 + lane;
    f32x2 acc2[4];
    #pragma unroll
    for (int p = 0; p < 4; p++) { acc2[p].x = 0.f; acc2[p].y = 0.f; }
    #pragma unroll
    for (int ii = 0; ii < 8; ii++) {
        int i = wave * 8 + ii;
        float w = Wb[(size_t)i * 64];                 // coalesced
        f32x2 w2; w2.x = w; w2.y = w;
        const float* gr = &gsT[i][0];
        float4 ga = *(const float4*)(gr);             // nodes 0..3 (broadcast)
        float4 gb = *(const float4*)(gr + 4);         // nodes 4..7 (broadcast)
        f32x2 p0; p0.x = ga.x; p0.y = ga.y; pk_fma(acc2[0], p0, w2);
        f32x2 p1; p1.x = ga.z; p1.y = ga.w; pk_fma(acc2[1], p1, w2);
        f32x2 p2; p2.x = gb.x; p2.y = gb.y; pk_fma(acc2[2], p2, w2);
        f32x2 p3; p3.x = gb.z; p3.y = gb.w; pk_fma(acc2[3], p3, w2);
    }
    #pragma unroll
    for (int p = 0; p < 4; p++) {
        part[wave][2 * p][lane]     = acc2[p].x;
        part[wave][2 * p + 1][lane] = acc2[p].y;
    }
    __syncthreads();
    // wave g reduces node g (same node the wave gathered: node = blk*8+wave)
    float s = bb;
    #pragma unroll
    for (int gg = 0; gg < 8; gg++) s += part[gg][wave][lane];   // conflict-free
    float r = gk * s + (1.f - gk) * hprev;
    r = fmaxf(r, 0.f);                                   // relu
    if (!last) {
        h[(size_t)node * 64 + lane] = r;
    } else {                                             // fused l2 normalize
        float ss = r * r;
        ss += __shfl_xor(ss, 1, 64);  ss += __shfl_xor(ss, 2, 64);
        ss += __shfl_xor(ss, 4, 64);  ss += __shfl_xor(ss, 8, 64);
        ss += __shfl_xor(ss, 16, 64); ss += __shfl_xor(ss, 32, 64);
        float nrm = fmaxf(sqrtf(ss), 1e-12f);
        out[(size_t)node * 64 + lane] = r / nrm;
    }
}

extern "C" void kernel_launch(void* const* d_in, const int* in_sizes, int n_in,
                              void* d_out, int out_size, void* d_ws, size_t ws_size,
                              hipStream_t stream) {
    const float* xu   = (const float*)d_in[0];
    const float* xe   = (const float*)d_in[1];
    const float* xv   = (const float*)d_in[2];
    const float* Wu   = (const float*)d_in[3];
    const float* bu   = (const float*)d_in[4];
    const float* We   = (const float*)d_in[5];
    const float* be   = (const float*)d_in[6];
    const float* Wv_  = (const float*)d_in[7];
    const float* bv   = (const float*)d_in[8];
    const float* embu = (const float*)d_in[9];
    const float* embe = (const float*)d_in[10];
    const float* embv = (const float*)d_in[11];
    const float* Wkqv = (const float*)d_in[12];
    const float* bkqv = (const float*)d_in[13];
    const float* Wk   = (const float*)d_in[14];
    const float* Wv   = (const float*)d_in[15];
    const float* prel = (const float*)d_in[16];
    const float* Wout = (const float*)d_in[17];
    const float* bout = (const float*)d_in[18];
    const float* skip = (const float*)d_in[19];
    const int*   idu  = (const int*)d_in[20];
    const int*   ide  = (const int*)d_in[21];
    const int*   idv  = (const int*)d_in[22];
    EdgePtrs ep;
    for (int e = 0; e < 13; e++) ep.p[e] = (const int*)d_in[23 + e];

    float* ws  = (float*)d_ws;
    float* h      = ws;                                    // NTOT*64 f32
    float* qagg   = h    + (size_t)NTOT * HID;             // NTOT*64 f32 (q)
    __half2* kvt  = (__half2*)(qagg + (size_t)NTOT * HID); // NSLOT*64 half2
    int* cnt     = (int*)(kvt + (size_t)NSLOT * HID);      // NTOT
    int* row_ptr = cnt + NTOT;                             // NTOT+1
    int* partial = row_ptr + NTOT + 1;                     // 512
    int* csr     = partial + 512;                          // ETOT int
    int* pos     = csr + ETOT;                             // ETOT int

    k_init<<<(NTOT + 15) / 16, 64, 0, stream>>>(
        xu, xe, xv, Wu, bu, We, be, Wv_, bv, embu, embe, embv, idu, ide, idv, h);

    // CSR build (edges are layer-invariant); exact rows, entry = slot id
    hipMemsetAsync(cnt, 0, (size_t)NTOT * 4, stream);
    int nblk = (NTOT + 255) / 256;   // 356
    k_cnt<<<(ETOT + 255) / 256, 256, 0, stream>>>(ep, cnt, pos);
    k_scan_a<<<nblk, 256, 0, stream>>>(cnt, partial);
    k_scan_b<<<1, 512, 0, stream>>>(partial, nblk);
    k_scan_c<<<nblk, 256, 0, stream>>>(cnt, partial, row_ptr);
    k_fill<<<(ETOT + 255) / 256, 256, 0, stream>>>(ep, row_ptr, pos, csr);

    for (int l = 0; l < LAYERS; l++) {
        k_kqvt<<<(NTOT + 15) / 16, 192, 0, stream>>>(h, Wkqv, bkqv, Wk, Wv, prel,
                                                     qagg, kvt, l);
        k_gather<<<NTOT / 8, 512, 0, stream>>>(qagg, kvt, row_ptr, csr,
                                               Wout, bout, skip, h,
                                               (float*)d_out, l, l == LAYERS - 1);
    }
}

// Round 15
// 582.760 us; speedup vs baseline: 1.0314x; 1.0314x over previous
//
#include <hip/hip_runtime.h>
#include <hip/hip_fp16.h>
#include <math.h>

#define HID   64
#define HEADS 4
#define DH    16
#define NU    30000
#define NE_   60000
#define NV    1000
#define NTOT  91000
#define ETOT  870000
#define NSLOT 541000
#define LAYERS 2

// Edge-type tables
__device__ const int d_EOFF[14] = {0,150000,270000,330000,370000,400000,450000,
                                   570000,630000,670000,700000,750000,810000,870000};
__device__ const int d_ECNT[13] = {150000,120000,60000,40000,30000,50000,
                                   120000,60000,40000,30000,50000,60000,60000};
__device__ const int d_EST[13]  = {0,0,0,0,0,0,1,1,1,1,1,1,2};
__device__ const int d_EDT[13]  = {0,1,1,1,1,1,0,0,0,0,0,2,1};
__device__ const int d_NOFF[3]  = {0, NU, NU + NE_};
// slot base per edge type in the kvt mega-table (src-node indexed per e)
__device__ const int d_EBASE[13] = {0,30000,60000,90000,120000,150000,
                                    180000,240000,300000,360000,420000,480000,540000};

struct EdgePtrs { const int* p[13]; };

typedef float f32x2 __attribute__((ext_vector_type(2)));

__device__ __forceinline__ void pk_fma(f32x2& acc, f32x2 a, f32x2 b) {
    asm("v_pk_fma_f32 %0, %1, %2, %0" : "+v"(acc) : "v"(a), "v"(b));
}
// a is wave-uniform (SGPR pair) -> VOP3P scalar source, no v_mov marshalling.
__device__ __forceinline__ void pk_fma_sv(f32x2& acc, f32x2 a_sgpr, f32x2 b) {
    asm("v_pk_fma_f32 %0, %1, %2, %0" : "+v"(acc) : "s"(a_sgpr), "v"(b));
}

__device__ __forceinline__ int node_type(int n) {
    return (n >= NU) + (n >= NU + NE_);
}

// ---------------- input projection: h = x@W + b + emb[ids] ----------------
__global__ __launch_bounds__(64)
void k_init(const float* __restrict__ xu, const float* __restrict__ xe,
            const float* __restrict__ xv,
            const float* __restrict__ Wu, const float* __restrict__ bu,
            const float* __restrict__ We, const float* __restrict__ be,
            const float* __restrict__ Wv_, const float* __restrict__ bv,
            const float* __restrict__ embu, const float* __restrict__ embe,
            const float* __restrict__ embv,
            const int* __restrict__ idu, const int* __restrict__ ide,
            const int* __restrict__ idv,
            float* __restrict__ h) {
    int n0 = blockIdx.x * 16;
    int t = node_type(n0);          // 16-node tiles never straddle type boundaries
    int j = threadIdx.x;            // output column 0..63
    const float *x, *W, *bb, *emb; const int* ids; int in_dim;
    if (t == 0)      { x = xu; W = Wu;  bb = bu; emb = embu; ids = idu; in_dim = 32; }
    else if (t == 1) { x = xe; W = We;  bb = be; emb = embe; ids = ide; in_dim = 32; }
    else             { x = xv; W = Wv_; bb = bv; emb = embv; ids = idv; in_dim = 16; }
    int nl = n0 - d_NOFF[t];
    int nn = min(16, NTOT - n0);
    __shared__ float xT[32][20];    // transposed x tile, +4 pad
    int ncs = (in_dim == 32) ? 3 : 2;       // log2 float4-chunks per node
    int nch = 1 << ncs;
    for (int idx = j; idx < (nch << 4); idx += 64) {
        int n = idx >> ncs, c = idx & (nch - 1);
        float4 v = make_float4(0.f, 0.f, 0.f, 0.f);
        if (n < nn) v = *(const float4*)(x + (size_t)(nl + n) * in_dim + c * 4);
        xT[c * 4 + 0][n] = v.x;
        xT[c * 4 + 1][n] = v.y;
        xT[c * 4 + 2][n] = v.z;
        xT[c * 4 + 3][n] = v.w;
    }
    __syncthreads();
    float bj = bb[j];
    f32x2 acc2[8];
    #pragma unroll
    for (int p = 0; p < 8; p++) {
        float ex = (2 * p     < nn) ? emb[(size_t)ids[nl + 2 * p    ] * 64 + j] : 0.f;
        float ey = (2 * p + 1 < nn) ? emb[(size_t)ids[nl + 2 * p + 1] * 64 + j] : 0.f;
        acc2[p].x = bj + ex; acc2[p].y = bj + ey;
    }
    if (in_dim == 32) {
        #pragma unroll
        for (int i = 0; i < 32; i++) {
            float w = W[i * 64 + j];
            f32x2 w2; w2.x = w; w2.y = w;
            #pragma unroll
            for (int qd = 0; qd < 4; qd++) {
                float4 hv = *(const float4*)(&xT[i][qd * 4]);
                f32x2 p0; p0.x = hv.x; p0.y = hv.y; pk_fma(acc2[2 * qd],     p0, w2);
                f32x2 p1; p1.x = hv.z; p1.y = hv.w; pk_fma(acc2[2 * qd + 1], p1, w2);
            }
        }
    } else {
        #pragma unroll
        for (int i = 0; i < 16; i++) {
            float w = W[i * 64 + j];
            f32x2 w2; w2.x = w; w2.y = w;
            #pragma unroll
            for (int qd = 0; qd < 4; qd++) {
                float4 hv = *(const float4*)(&xT[i][qd * 4]);
                f32x2 p0; p0.x = hv.x; p0.y = hv.y; pk_fma(acc2[2 * qd],     p0, w2);
                f32x2 p1; p1.x = hv.z; p1.y = hv.w; pk_fma(acc2[2 * qd + 1], p1, w2);
            }
        }
    }
    #pragma unroll
    for (int p = 0; p < 8; p++) {
        if (2 * p     < nn) h[(size_t)(n0 + 2 * p)     * 64 + j] = acc2[p].x;
        if (2 * p + 1 < nn) h[(size_t)(n0 + 2 * p + 1) * 64 + j] = acc2[p].y;
    }
}

// ---------------- CSR build (single-atomic-pass, R15) ----------------
__global__ void k_cnt(EdgePtrs ep, int* __restrict__ cnt, int* __restrict__ pos) {
    int eidx = blockIdx.x * blockDim.x + threadIdx.x;
    if (eidx >= ETOT) return;
    int e = 0;
    #pragma unroll
    for (int i = 1; i < 13; i++) e += (eidx >= d_EOFF[i]);
    int li = eidx - d_EOFF[e];
    int dst = ep.p[e][d_ECNT[e] + li];
    pos[eidx] = atomicAdd(&cnt[d_NOFF[d_EDT[e]] + dst], 1);
}

__global__ void k_scan_a(const int* __restrict__ cnt, int* __restrict__ partial) {
    __shared__ int s[256];
    int i = blockIdx.x * 256 + threadIdx.x;
    s[threadIdx.x] = (i < NTOT) ? cnt[i] : 0;
    __syncthreads();
    for (int off = 128; off > 0; off >>= 1) {
        if (threadIdx.x < off) s[threadIdx.x] += s[threadIdx.x + off];
        __syncthreads();
    }
    if (threadIdx.x == 0) partial[blockIdx.x] = s[0];
}

__global__ void k_scan_b(int* __restrict__ partial, int nblk) {
    __shared__ int s[512];
    int t = threadIdx.x;
    s[t] = (t < nblk) ? partial[t] : 0;
    __syncthreads();
    for (int off = 1; off < 512; off <<= 1) {
        int v = (t >= off) ? s[t - off] : 0;
        __syncthreads();
        s[t] += v;
        __syncthreads();
    }
    if (t < nblk) partial[t] = t ? s[t - 1] : 0;   // exclusive
}

__global__ void k_scan_c(const int* __restrict__ cnt, const int* __restrict__ partial,
                         int* __restrict__ row_ptr) {
    __shared__ int s[256];
    int i = blockIdx.x * 256 + threadIdx.x, t = threadIdx.x;
    int v = (i < NTOT) ? cnt[i] : 0;
    s[t] = v;
    __syncthreads();
    for (int off = 1; off < 256; off <<= 1) {
        int u = (t >= off) ? s[t - off] : 0;
        __syncthreads();
        s[t] += u;
        __syncthreads();
    }
    if (i < NTOT) row_ptr[i] = s[t] - v + partial[blockIdx.x];
    if (i == NTOT - 1) row_ptr[NTOT] = s[t] + partial[blockIdx.x];
}

__global__ void k_fill(EdgePtrs ep, const int* __restrict__ row_ptr,
                       const int* __restrict__ pos, int* __restrict__ csr) {
    int eidx = blockIdx.x * blockDim.x + threadIdx.x;
    if (eidx >= ETOT) return;
    int e = 0;
    #pragma unroll
    for (int i = 1; i < 13; i++) e += (eidx >= d_EOFF[i]);
    int li = eidx - d_EOFF[e];
    const int* base = ep.p[e];
    int src = base[li], dst = base[d_ECNT[e] + li];
    int dg = d_NOFF[d_EDT[e]] + dst;
    csr[row_ptr[dg] + pos[eidx]] = d_EBASE[e] + src;   // no atomic
}

// ---------------- fused kqv projection + kvt slot table build ----------------
// R12 structure (local optimum: 95.5us, VALU+DS co-bound).
__global__ __launch_bounds__(192, 3)
void k_kqvt(const float* __restrict__ h, const float* __restrict__ Wkqv,
            const float* __restrict__ bkqv, const float* __restrict__ Wk,
            const float* __restrict__ Wv, const float* __restrict__ prel,
            float* __restrict__ qagg, __half2* __restrict__ kvt, int layer) {
    int n0 = blockIdx.x * 16;
    int t = node_type(n0);          // 16-node tiles never straddle type boundaries
    __shared__ float kq[16][192];   // per node: k 0..63 | q 64..127 | v 128..191
    int j = threadIdx.x;

    // ---- stage 1: column j of kqv for 16 nodes; uniform global h reads
    const float* hb = h + (size_t)n0 * 64;
    const float* Wc = Wkqv + (size_t)(layer * 3 + t) * HID * 192 + j;
    float b = bkqv[(layer * 3 + t) * 192 + j];
    f32x2 acc2[16];
    #pragma unroll
    for (int n = 0; n < 16; n++) { acc2[n].x = 0.f; acc2[n].y = 0.f; }
    #pragma unroll
    for (int ic = 0; ic < 16; ic++) {
        float w0 = Wc[(size_t)(4 * ic + 0) * 192];
        float w1 = Wc[(size_t)(4 * ic + 1) * 192];
        float w2 = Wc[(size_t)(4 * ic + 2) * 192];
        float w3 = Wc[(size_t)(4 * ic + 3) * 192];
        f32x2 wA; wA.x = w0; wA.y = w1;
        f32x2 wB; wB.x = w2; wB.y = w3;
        #pragma unroll
        for (int n = 0; n < 16; n++) {
            float4 hv = *(const float4*)(hb + n * 64 + ic * 4);  // block-uniform
            f32x2 p0; p0.x = hv.x; p0.y = hv.y;
            pk_fma_sv(acc2[n], p0, wA);
            f32x2 p1; p1.x = hv.z; p1.y = hv.w;
            pk_fma_sv(acc2[n], p1, wB);
        }
    }
    float accf[16];
    #pragma unroll
    for (int n = 0; n < 16; n++) accf[n] = b + acc2[n].x + acc2[n].y;
    #pragma unroll
    for (int n = 0; n < 16; n++) kq[n][j] = accf[n];
    if (j >= 64 && j < 128) {
        #pragma unroll
        for (int n = 0; n < 16; n++)
            if (n0 + n < NTOT) qagg[(size_t)(n0 + n) * 64 + (j - 64)] = accf[n];
    }
    __syncthreads();

    // ---- stage 2: emit kvt slots for the edge types sourced by this node type
    int wave = j >> 6, lane = j & 63;
    int hh = lane >> 4, xo = lane & 15;
    int ne = (t == 2) ? 1 : 6;
    int e0 = (t == 0) ? 0 : (t == 1) ? 6 : 12;
    int eA = e0 + wave, eB = e0 + wave + 3;
    bool vA = wave < ne, vB = wave + 3 < ne;
    int nt = n0 - d_NOFF[t];
    f32x2 wkA[8], wvA[8], wkB[8], wvB[8];
    int sbA = 0, sbB = 0;
    if (vA) {
        const float* Wkp = Wk + (((size_t)layer * 13 + eA) * 4 + hh) * 256 + xo;
        const float* Wvp = Wv + (((size_t)layer * 13 + eA) * 4 + hh) * 256 + xo;
        float pr = prel[(layer * 13 + eA) * 4 + hh] * 0.25f;
        #pragma unroll
        for (int p = 0; p < 8; p++) {
            wkA[p].x = Wkp[(2 * p)     * 16] * pr;
            wkA[p].y = Wkp[(2 * p + 1) * 16] * pr;
            wvA[p].x = Wvp[(2 * p)     * 16];
            wvA[p].y = Wvp[(2 * p + 1) * 16];
        }
        sbA = d_EBASE[eA] + nt;
    }
    if (vB) {
        const float* Wkp = Wk + (((size_t)layer * 13 + eB) * 4 + hh) * 256 + xo;
        const float* Wvp = Wv + (((size_t)layer * 13 + eB) * 4 + hh) * 256 + xo;
        float pr = prel[(layer * 13 + eB) * 4 + hh] * 0.25f;
        #pragma unroll
        for (int p = 0; p < 8; p++) {
            wkB[p].x = Wkp[(2 * p)     * 16] * pr;
            wkB[p].y = Wkp[(2 * p + 1) * 16] * pr;
            wvB[p].x = Wvp[(2 * p)     * 16];
            wvB[p].y = Wvp[(2 * p + 1) * 16];
        }
        sbB = d_EBASE[eB] + nt;
    }
    #pragma unroll
    for (int n = 0; n < 16; n++) {
        bool ok = (n0 + n) < NTOT;                 // uniform; false only in tail tile
        const float* kr = &kq[n][hh * 16];
        const float* vr = &kq[n][128 + hh * 16];
        float4 k0 = ((const float4*)kr)[0];
        float4 k1 = ((const float4*)kr)[1];
        float4 k2 = ((const float4*)kr)[2];
        float4 k3 = ((const float4*)kr)[3];
        float4 v0 = ((const float4*)vr)[0];
        float4 v1 = ((const float4*)vr)[1];
        float4 v2 = ((const float4*)vr)[2];
        float4 v3 = ((const float4*)vr)[3];
        if (vA & ok) {
            f32x2 ak; ak.x = 0.f; ak.y = 0.f;
            f32x2 av; av.x = 0.f; av.y = 0.f;
            f32x2 p0;
            p0.x = k0.x; p0.y = k0.y; pk_fma(ak, p0, wkA[0]);
            p0.x = k0.z; p0.y = k0.w; pk_fma(ak, p0, wkA[1]);
            p0.x = k1.x; p0.y = k1.y; pk_fma(ak, p0, wkA[2]);
            p0.x = k1.z; p0.y = k1.w; pk_fma(ak, p0, wkA[3]);
            p0.x = k2.x; p0.y = k2.y; pk_fma(ak, p0, wkA[4]);
            p0.x = k2.z; p0.y = k2.w; pk_fma(ak, p0, wkA[5]);
            p0.x = k3.x; p0.y = k3.y; pk_fma(ak, p0, wkA[6]);
            p0.x = k3.z; p0.y = k3.w; pk_fma(ak, p0, wkA[7]);
            p0.x = v0.x; p0.y = v0.y; pk_fma(av, p0, wvA[0]);
            p0.x = v0.z; p0.y = v0.w; pk_fma(av, p0, wvA[1]);
            p0.x = v1.x; p0.y = v1.y; pk_fma(av, p0, wvA[2]);
            p0.x = v1.z; p0.y = v1.w; pk_fma(av, p0, wvA[3]);
            p0.x = v2.x; p0.y = v2.y; pk_fma(av, p0, wvA[4]);
            p0.x = v2.z; p0.y = v2.w; pk_fma(av, p0, wvA[5]);
            p0.x = v3.x; p0.y = v3.y; pk_fma(av, p0, wvA[6]);
            p0.x = v3.z; p0.y = v3.w; pk_fma(av, p0, wvA[7]);
            float kt = ak.x + ak.y;
            float vt = av.x + av.y;
            kvt[(size_t)(sbA + n) * 64 + lane] = __float22half2_rn(make_float2(kt, vt));
        }
        if (vB & ok) {
            f32x2 ak; ak.x = 0.f; ak.y = 0.f;
            f32x2 av; av.x = 0.f; av.y = 0.f;
            f32x2 p0;
            p0.x = k0.x; p0.y = k0.y; pk_fma(ak, p0, wkB[0]);
            p0.x = k0.z; p0.y = k0.w; pk_fma(ak, p0, wkB[1]);
            p0.x = k1.x; p0.y = k1.y; pk_fma(ak, p0, wkB[2]);
            p0.x = k1.z; p0.y = k1.w; pk_fma(ak, p0, wkB[3]);
            p0.x = k2.x; p0.y = k2.y; pk_fma(ak, p0, wkB[4]);
            p0.x = k2.z; p0.y = k2.w; pk_fma(ak, p0, wkB[5]);
            p0.x = k3.x; p0.y = k3.y; pk_fma(ak, p0, wkB[6]);
            p0.x = k3.z; p0.y = k3.w; pk_fma(ak, p0, wkB[7]);
            p0.x = v0.x; p0.y = v0.y; pk_fma(av, p0, wvB[0]);
            p0.x = v0.z; p0.y = v0.w; pk_fma(av, p0, wvB[1]);
            p0.x = v1.x; p0.y = v1.y; pk_fma(av, p0, wvB[2]);
            p0.x = v1.z; p0.y = v1.w; pk_fma(av, p0, wvB[3]);
            p0.x = v2.x; p0.y = v2.y; pk_fma(av, p0, wvB[4]);
            p0.x = v2.z; p0.y = v2.w; pk_fma(av, p0, wvB[5]);
            p0.x = v3.x; p0.y = v3.y; pk_fma(av, p0, wvB[6]);
            p0.x = v3.z; p0.y = v3.w; pk_fma(av, p0, wvB[7]);
            float kt = ak.x + ak.y;
            float vt = av.x + av.y;
            kvt[(size_t)(sbB + n) * 64 + lane] = __float22half2_rn(make_float2(kt, vt));
        }
    }
}

// -------- fused gather + cooperative epilogue (R17, measured best) --------
__device__ __forceinline__ float row_sum16(float x) {
    int v;
    v = __builtin_amdgcn_update_dpp(0, __float_as_int(x), 0xB1, 0xF, 0xF, true); // quad_perm [1,0,3,2] : xor1
    x += __int_as_float(v);
    v = __builtin_amdgcn_update_dpp(0, __float_as_int(x), 0x4E, 0xF, 0xF, true); // quad_perm [2,3,0,1] : xor2
    x += __int_as_float(v);
    v = __builtin_amdgcn_update_dpp(0, __float_as_int(x), 0x141, 0xF, 0xF, true); // row_half_mirror : xor4
    x += __int_as_float(v);
    v = __builtin_amdgcn_update_dpp(0, __float_as_int(x), 0x140, 0xF, 0xF, true); // row_mirror : xor8
    x += __int_as_float(v);
    return x;
}

__device__ __forceinline__ void osm_step(float s, float vv,
                                         float& m, float& l, float& acc) {
    float d = s - m;
    float t = __expf(-fabsf(d));    // one exp per edge
    bool pos = d > 0.f;
    m = fmaxf(m, s);
    float sc = pos ? t : 1.f;
    float es = pos ? 1.f : t;
    l   = l * sc + es;
    acc = acc * sc + es * vv;
}

__global__ __launch_bounds__(512, 4)
void k_gather(const float* __restrict__ qagg, const __half2* __restrict__ kvt,
              const int* __restrict__ row_ptr, const int* __restrict__ csr,
              const float* __restrict__ Wout, const float* __restrict__ bout,
              const float* __restrict__ skip,
              float* __restrict__ h, float* __restrict__ out,
              int layer, int last) {
    int wave = threadIdx.x >> 6, lane = threadIdx.x & 63;
    int node = blockIdx.x * 8 + wave;            // grid is exact: no tail
    int t = node_type(node);                     // block-uniform
    // prefetches whose latency hides under the gather loop
    float hprev = h[(size_t)node * 64 + lane];
    float bb = bout[(layer * 3 + t) * 64 + lane];
    float gk = 1.f / (1.f + __expf(-skip[layer * 3 + t]));
    float q = qagg[(size_t)node * 64 + lane];    // q[h][x]
    int beg = row_ptr[node], end = row_ptr[node + 1];
    float m0 = -1e30f, l0 = 0.f, a0 = 0.f;       // chain 0 (edges k%4==0)
    float m1 = -1e30f, l1 = 0.f, a1 = 0.f;       // chain 1
    float m2 = -1e30f, l2 = 0.f, a2 = 0.f;       // chain 2
    float m3 = -1e30f, l3 = 0.f, a3 = 0.f;       // chain 3
    for (int base = beg; base < end; base += 64) {
        int n = end - base; if (n > 64) n = 64;
        int ent = csr[base + ((lane < n) ? lane : 0)];   // 64 entries in one load
        for (int c = 0; c < n; c += 8) {
            int cn = n - c; if (cn > 8) cn = 8;
            __half2 f[8];
            #pragma unroll
            for (int k = 0; k < 8; k++) {               // batch 8 gathers (MLP)
                int idx = c + ((k < cn) ? k : 0);
                int sl = __shfl(ent, idx, 64);
                f[k] = kvt[(size_t)sl * 64 + lane];
            }
            float s8[8];
            #pragma unroll
            for (int k = 0; k < 8; k++) {               // 8 independent reductions
                if (k >= cn) break;                     // uniform branch
                s8[k] = row_sum16(q * __low2float(f[k]));
            }
            // 4 interleaved chains: dependent depth 2 per batch
            if (0 < cn) osm_step(s8[0], __high2float(f[0]), m0, l0, a0);
            if (1 < cn) osm_step(s8[1], __high2float(f[1]), m1, l1, a1);
            if (2 < cn) osm_step(s8[2], __high2float(f[2]), m2, l2, a2);
            if (3 < cn) osm_step(s8[3], __high2float(f[3]), m3, l3, a3);
            if (4 < cn) osm_step(s8[4], __high2float(f[4]), m0, l0, a0);
            if (5 < cn) osm_step(s8[5], __high2float(f[5]), m1, l1, a1);
            if (6 < cn) osm_step(s8[6], __high2float(f[6]), m2, l2, a2);
            if (7 < cn) osm_step(s8[7], __high2float(f[7]), m3, l3, a3);
        }
    }
    // merge the four online-softmax states
    float M   = fmaxf(fmaxf(m0, m1), fmaxf(m2, m3));
    float e0  = __expf(m0 - M), e1 = __expf(m1 - M);
    float e2  = __expf(m2 - M), e3 = __expf(m3 - M);
    float l   = l0 * e0 + l1 * e1 + l2 * e2 + l3 * e3;
    float acc = a0 * e0 + a1 * e1 + a2 * e2 + a3 * e3;
    float og  = (l > 0.f) ? acc / l : 0.f;

    // ---- cooperative epilogue ----
    float gl = 0.5f * og * (1.f + erff(og * 0.70710678118654752f));   // gelu
    __shared__ float gsT[64][12];       // gsT[i][n]; 48B rows (16B-aligned)
    __shared__ float part[8][8][64];    // part[g][n][j]
    gsT[lane][wave] = gl;
    __syncthreads();
    // thread (g=wave, j=lane): partial over i in [8g, 8g+8) for all 8 nodes
    const float* Wb = Wout + (size_t)(layer * 3 + t) * 4096 + lane;
    f32x2 acc2[4];
    #pragma unroll
    for (int p = 0; p < 4; p++) { acc2[p].x = 0.f; acc2[p].y = 0.f; }
    #pragma unroll
    for (int ii = 0; ii < 8; ii++) {
        int i = wave * 8 + ii;
        float w = Wb[(size_t)i * 64];                 // coalesced
        f32x2 w2; w2.x = w; w2.y = w;
        const float* gr = &gsT[i][0];
        float4 ga = *(const float4*)(gr);             // nodes 0..3 (broadcast)
        float4 gb = *(const float4*)(gr + 4);         // nodes 4..7 (broadcast)
        f32x2 p0; p0.x = ga.x; p0.y = ga.y; pk_fma(acc2[0], p0, w2);
        f32x2 p1; p1.x = ga.z; p1.y = ga.w; pk_fma(acc2[1], p1, w2);
        f32x2 p2; p2.x = gb.x; p2.y = gb.y; pk_fma(acc2[2], p2, w2);
        f32x2 p3; p3.x = gb.z; p3.y = gb.w; pk_fma(acc2[3], p3, w2);
    }
    #pragma unroll
    for (int p = 0; p < 4; p++) {
        part[wave][2 * p][lane]     = acc2[p].x;
        part[wave][2 * p + 1][lane] = acc2[p].y;
    }
    __syncthreads();
    // wave g reduces node g (same node the wave gathered: node = blk*8+wave)
    float s = bb;
    #pragma unroll
    for (int gg = 0; gg < 8; gg++) s += part[gg][wave][lane];   // conflict-free
    float r = gk * s + (1.f - gk) * hprev;
    r = fmaxf(r, 0.f);                                   // relu
    if (!last) {
        h[(size_t)node * 64 + lane] = r;
    } else {                                             // fused l2 normalize
        float ss = r * r;
        ss += __shfl_xor(ss, 1, 64);  ss += __shfl_xor(ss, 2, 64);
        ss += __shfl_xor(ss, 4, 64);  ss += __shfl_xor(ss, 8, 64);
        ss += __shfl_xor(ss, 16, 64); ss += __shfl_xor(ss, 32, 64);
        float nrm = fmaxf(sqrtf(ss), 1e-12f);
        out[(size_t)node * 64 + lane] = r / nrm;
    }
}

extern "C" void kernel_launch(void* const* d_in, const int* in_sizes, int n_in,
                              void* d_out, int out_size, void* d_ws, size_t ws_size,
                              hipStream_t stream) {
    const float* xu   = (const float*)d_in[0];
    const float* xe   = (const float*)d_in[1];
    const float* xv   = (const float*)d_in[2];
    const float* Wu   = (const float*)d_in[3];
    const float* bu   = (const float*)d_in[4];
    const float* We   = (const float*)d_in[5];
    const float* be   = (const float*)d_in[6];
    const float* Wv_  = (const float*)d_in[7];
    const float* bv   = (const float*)d_in[8];
    const float* embu = (const float*)d_in[9];
    const float* embe = (const float*)d_in[10];
    const float* embv = (const float*)d_in[11];
    const float* Wkqv = (const float*)d_in[12];
    const float* bkqv = (const float*)d_in[13];
    const float* Wk   = (const float*)d_in[14];
    const float* Wv   = (const float*)d_in[15];
    const float* prel = (const float*)d_in[16];
    const float* Wout = (const float*)d_in[17];
    const float* bout = (const float*)d_in[18];
    const float* skip = (const float*)d_in[19];
    const int*   idu  = (const int*)d_in[20];
    const int*   ide  = (const int*)d_in[21];
    const int*   idv  = (const int*)d_in[22];
    EdgePtrs ep;
    for (int e = 0; e < 13; e++) ep.p[e] = (const int*)d_in[23 + e];

    float* ws  = (float*)d_ws;
    float* h      = ws;                                    // NTOT*64 f32
    float* qagg   = h    + (size_t)NTOT * HID;             // NTOT*64 f32 (q)
    __half2* kvt  = (__half2*)(qagg + (size_t)NTOT * HID); // NSLOT*64 half2
    int* cnt     = (int*)(kvt + (size_t)NSLOT * HID);      // NTOT
    int* row_ptr = cnt + NTOT;                             // NTOT+1
    int* partial = row_ptr + NTOT + 1;                     // 512
    int* csr     = partial + 512;                          // ETOT int
    int* pos     = csr + ETOT;                             // ETOT int

    k_init<<<(NTOT + 15) / 16, 64, 0, stream>>>(
        xu, xe, xv, Wu, bu, We, be, Wv_, bv, embu, embe, embv, idu, ide, idv, h);

    // CSR build (edges are layer-invariant); exact rows, entry = slot id
    hipMemsetAsync(cnt, 0, (size_t)NTOT * 4, stream);
    int nblk = (NTOT + 255) / 256;   // 356
    k_cnt<<<(ETOT + 255) / 256, 256, 0, stream>>>(ep, cnt, pos);
    k_scan_a<<<nblk, 256, 0, stream>>>(cnt, partial);
    k_scan_b<<<1, 512, 0, stream>>>(partial, nblk);
    k_scan_c<<<nblk, 256, 0, stream>>>(cnt, partial, row_ptr);
    k_fill<<<(ETOT + 255) / 256, 256, 0, stream>>>(ep, row_ptr, pos, csr);

    for (int l = 0; l < LAYERS; l++) {
        k_kqvt<<<(NTOT + 15) / 16, 192, 0, stream>>>(h, Wkqv, bkqv, Wk, Wv, prel,
                                                     qagg, kvt, l);
        k_gather<<<NTOT / 8, 512, 0, stream>>>(qagg, kvt, row_ptr, csr,
                                               Wout, bout, skip, h,
                                               (float*)d_out, l, l == LAYERS - 1);
    }
}